// Round 8
// baseline (440.096 us; speedup 1.0000x reference)
//
#include <hip/hip_runtime.h>
#include <cstdint>
#include <cstddef>

constexpr int T_ = 128;
constexpr int S_ = 512;
constexpr int B_ = 256;
constexpr int START_ = T_ - 3;  // 125
constexpr int STOP_  = T_ - 2;  // 126

// Barrier that only drains LDS (lgkmcnt), NOT vmcnt: global ph-stores and
// e-prefetch loads legally stay in flight across it (thread-private data).
__device__ __forceinline__ void lds_barrier() {
  asm volatile("s_waitcnt lgkmcnt(0)\n\ts_barrier" ::: "memory");
}
__device__ __forceinline__ void lgkm_wait() {
  asm volatile("s_waitcnt lgkmcnt(0)" ::: "memory");
}

// readlane: wave-uniform lane index (SGPR) -> ~VALU-speed broadcast.
__device__ __forceinline__ float readlane_f(float v, int sl) {
  return __int_as_float(__builtin_amdgcn_readlane(__float_as_int(v), sl));
}

// max-reduce over the 16 ig-lanes (lane bits [0,4)) in pure row-DPP
// (verified bit-exact in R7): quad xor1 (0xB1), quad xor2 (0x4E),
// row_half_mirror (0x141), row_mirror (0x140).
__device__ __forceinline__ float ig16_rmax(float m) {
  int x = __builtin_amdgcn_mov_dpp(__float_as_int(m), 0xB1, 0xF, 0xF, true);
  m = fmaxf(m, __int_as_float(x));
  x = __builtin_amdgcn_mov_dpp(__float_as_int(m), 0x4E, 0xF, 0xF, true);
  m = fmaxf(m, __int_as_float(x));
  x = __builtin_amdgcn_mov_dpp(__float_as_int(m), 0x141, 0xF, 0xF, true);
  m = fmaxf(m, __int_as_float(x));
  x = __builtin_amdgcn_mov_dpp(__float_as_int(m), 0x140, 0xF, 0xF, true);
  m = fmaxf(m, __int_as_float(x));
  return m;
}

// ---------------------------------------------------------------------------
// Forward: value-only Viterbi recursion, stores part_hist as (B,S,T) fp32
// (contiguous per-b rows -> trace can bulk-stage windows into LDS).
// R8 change: 1024 threads (16 waves = 4 waves/SIMD; R7's 2 waves/SIMD gave
// 303->266 µs, still latency-exposed). Thread (ig,jg): i in [8ig,8ig+8) x
// j = {2jg, 2jg+1}. Padded part LDS (granule pair 3ig,3ig+1: 2-way alias,
// free). Bit-exact: max exactly associative, fl monotone =>
// max_i fl(fl(p+tr)+e) == fl(max_i fl(p+tr) + e).
// ---------------------------------------------------------------------------
__global__ __launch_bounds__(1024, 4) void viterbi_forward(
    const float* __restrict__ feats,   // (B,S,T)
    const float* __restrict__ trans,   // (T,T)
    float* __restrict__ ph)            // (B,S,T) workspace
{
  const int b    = blockIdx.x;
  const int tid  = threadIdx.x;
  const int lane = tid & 63;
  const int ig   = lane & 15;          // i-chunk: i in [8ig, 8ig+8)
  const int jg   = tid >> 4;           // 0..63
  const int j0   = jg * 2;

  // padded part: value i at float offset i + 4*(i>>3); 192 floats/buffer
  __shared__ alignas(16) float part[2][192];

  // trans tile: tc[ii] = trans[8ig+ii][j0..j0+1] (16 VGPRs, fixed over t)
  float2 tc[8];
  #pragma unroll
  for (int ii = 0; ii < 8; ++ii)
    tc[ii] = *(const float2*)&trans[(8 * ig + ii) * T_ + j0];

  const float* fb  = feats + (size_t)b * S_ * T_;
  float*       phb = ph    + (size_t)b * S_ * T_;
  const int woff   = j0 + 4 * (j0 >> 3);

  // t = 0: part0 = emit[0] + trans[START,:]
  float2 e0 = *(const float2*)&fb[j0];
  float2 ts = *(const float2*)&trans[START_ * T_ + j0];
  float2 p0 = {e0.x + ts.x, e0.y + ts.y};
  if (ig == 0) {
    *(float2*)&part[0][woff] = p0;
    *(float2*)&phb[j0] = p0;
  }
  __syncthreads();

  auto stepf = [&](int t, float2 e2) {
    const float4* p4 = (const float4*)part[(t - 1) & 1];
    float4 pa = p4[3 * ig];
    float4 pb = p4[3 * ig + 1];
    const float pv[8] = {pa.x, pa.y, pa.z, pa.w, pb.x, pb.y, pb.z, pb.w};
    float m0, m1;
    {
      float a0 = pv[0] + tc[0].x, a1 = pv[1] + tc[1].x;
      float a2 = pv[2] + tc[2].x, a3 = pv[3] + tc[3].x;
      float a4 = pv[4] + tc[4].x, a5 = pv[5] + tc[5].x;
      float a6 = pv[6] + tc[6].x, a7 = pv[7] + tc[7].x;
      m0 = ig16_rmax(fmaxf(fmaxf(fmaxf(a0, a1), fmaxf(a2, a3)),
                           fmaxf(fmaxf(a4, a5), fmaxf(a6, a7))));
    }
    {
      float a0 = pv[0] + tc[0].y, a1 = pv[1] + tc[1].y;
      float a2 = pv[2] + tc[2].y, a3 = pv[3] + tc[3].y;
      float a4 = pv[4] + tc[4].y, a5 = pv[5] + tc[5].y;
      float a6 = pv[6] + tc[6].y, a7 = pv[7] + tc[7].y;
      m1 = ig16_rmax(fmaxf(fmaxf(fmaxf(a0, a1), fmaxf(a2, a3)),
                           fmaxf(fmaxf(a4, a5), fmaxf(a6, a7))));
    }
    float2 np = {m0 + e2.x, m1 + e2.y};
    if (ig == 0) *(float2*)&part[t & 1][woff] = np;
    lds_barrier();
    if (ig == 0)
      *(float2*)&phb[(size_t)t * T_ + j0] = np;   // off critical path
  };

  // emission prefetch: 8 rows in flight (named A/B groups of 4)
  float2 EA[4], EB[4];
  #pragma unroll
  for (int u = 0; u < 4; ++u)
    EA[u] = *(const float2*)&fb[(size_t)(1 + u) * T_ + j0];

  for (int t0 = 1; t0 < S_; t0 += 8) {
    #pragma unroll
    for (int u = 0; u < 4; ++u) {
      int tr = t0 + 4 + u; if (tr > S_ - 1) tr = S_ - 1;
      EB[u] = *(const float2*)&fb[(size_t)tr * T_ + j0];
    }
    #pragma unroll
    for (int u = 0; u < 4; ++u) { int t = t0 + u; if (t < S_) stepf(t, EA[u]); }
    #pragma unroll
    for (int u = 0; u < 4; ++u) {
      int tr = t0 + 8 + u; if (tr > S_ - 1) tr = S_ - 1;
      EA[u] = *(const float2*)&fb[(size_t)tr * T_ + j0];
    }
    #pragma unroll
    for (int u = 0; u < 4; ++u) { int t = t0 + 4 + u; if (t < S_) stepf(t, EB[u]); }
  }
}

// ---------------------------------------------------------------------------
// Trace R8: all-LDS chase. One wave per b. ph/feats rows staged in 16-step
// windows into double-buffered LDS; loads for window w-1 are issued BEFORE
// chasing window w (~2400 cyc slack >> HBM latency), so the serial chain is
// pure LDS: tr-gather + P-row ds_read (parallel ~120 cyc) -> 2 adds -> cmp/
// ballot -> ffs/min ~= 160 cyc/step. tg via readlane of in-register P row;
// e via off-chain LDS broadcast read issued one step ahead. Bit-exact
// first-occurrence argmax (equality-ballot) vs reference.
// ---------------------------------------------------------------------------
constexpr int TS_ = 130;  // transT row stride
constexpr int WS_ = 16;   // window steps

__global__ __launch_bounds__(64, 1) void viterbi_trace(
    const float* __restrict__ feats,   // (B,S,T)
    const void*  __restrict__ mask,    // (B,S) dtype detected at runtime
    const float* __restrict__ trans,   // (T,T)
    const float* __restrict__ ph,      // (B,S,T)
    int* __restrict__ out)             // (B,S) int32
{
  const int b    = blockIdx.x;
  const int lane = threadIdx.x;

  __shared__ alignas(16) float transT[T_ * TS_];  // transT[j*TS+i]=trans[i][j]
  __shared__ alignas(16) float phs[2][WS_ * T_];  // 8 KB each
  __shared__ alignas(16) float fes[2][WS_ * T_];

  #pragma unroll 4
  for (int g = lane; g < T_ * T_; g += 64) {
    int i = g >> 7, jj = g & (T_ - 1);
    transT[jj * TS_ + i] = trans[g];
  }
  __syncthreads();

  // ---- sequence length (mask dtype: uint8 / float32 / int32) ----
  int len = 0;
  {
    const int w0m = *(const int*)mask;  // element (0,0) is always true
    if (w0m == 0x01010101) {
      const unsigned char* m = (const unsigned char*)mask + (size_t)b * S_;
      for (int s = lane; s < S_; s += 64) len += (m[s] != 0);
    } else if (w0m == 0x3F800000) {
      const float* m = (const float*)mask + (size_t)b * S_;
      for (int s = lane; s < S_; s += 64) len += (m[s] != 0.0f);
    } else {
      const int* m = (const int*)mask + (size_t)b * S_;
      for (int s = lane; s < S_; s += 64) len += (m[s] != 0);
    }
    #pragma unroll
    for (int o = 32; o > 0; o >>= 1) len += __shfl_xor(len, o);
  }
  const int lp = len - 1;              // last valid position (>= 255)

  const float* phb = ph    + (size_t)b * S_ * T_;
  const float* fb  = feats + (size_t)b * S_ * T_;

  // ---- final pointer: first argmax_i(ph_lp[i] + trans[i][STOP]) ----
  const float2 L = *(const float2*)(phb + (size_t)lp * T_ + 2 * lane);
  float v0 = L.x + transT[STOP_ * TS_ + 2 * lane];
  float v1 = L.y + transT[STOP_ * TS_ + 2 * lane + 1];
  float mx = fmaxf(v0, v1);
  #pragma unroll
  for (int o = 32; o > 0; o >>= 1) mx = fmaxf(mx, __shfl_xor(mx, o));
  unsigned long long g0 = __ballot(v0 == mx);
  unsigned long long g1 = __ballot(v1 == mx);
  int p0 = g0 ? 2 * (__ffsll(g0) - 1)     : (1 << 30);
  int p1 = g1 ? 2 * (__ffsll(g1) - 1) + 1 : (1 << 30);
  const int pointer = min(p0, p1);

  // ---- masked tail: out[k]=0 for lp<k<S-1; out[S-1]=out[lp]=pointer ----
  for (int k = lp + 1 + lane; k <= S_ - 2; k += 64) out[b * S_ + k] = 0;
  if (lane == 0) {
    out[b * S_ + (S_ - 1)] = pointer;
    if (lp < S_ - 1) out[b * S_ + lp] = pointer;
  }

  // ---- chase k = lp-1 .. 0 in 16-step LDS windows ----
  int   ptr = pointer;
  float tg  = readlane_f((ptr & 1) ? L.y : L.x, ptr >> 1);   // ph[lp][ptr]
  const float2 FL = *(const float2*)(fb + (size_t)lp * T_ + 2 * lane);
  float e = readlane_f((ptr & 1) ? FL.y : FL.x, ptr >> 1);   // feats[lp][ptr]

  float4 RP[8], RF[8];   // staging regs: one window = 16 rows x 512 B each

  auto load_regs = [&](int w) {
    const float4* gp = (const float4*)(phb + (size_t)(WS_ * w) * T_);
    const float4* gf = (const float4*)(fb  + (size_t)(WS_ * w) * T_);
    #pragma unroll
    for (int q = 0; q < 8; ++q) {
      RP[q] = gp[q * 64 + lane];
      RF[q] = gf[q * 64 + lane];
    }
  };
  auto write_lds = [&](int buf) {
    float4* dp = (float4*)phs[buf];
    float4* df = (float4*)fes[buf];
    #pragma unroll
    for (int q = 0; q < 8; ++q) {
      dp[q * 64 + lane] = RP[q];
      df[q * 64 + lane] = RF[q];
    }
    lgkm_wait();   // LDS writes visible to this wave's subsequent reads
  };

  const int w0 = (lp - 1) >> 4;
  load_regs(w0);
  write_lds(0);
  int cur = 0;
  int khi = lp - 1;
  for (int w = w0; w >= 0; --w) {
    if (w > 0) load_regs(w - 1);       // in flight during this window's chase
    const int klo = WS_ * w;
    const float* Prow = phs[cur];
    const float* Frow = fes[cur];
    for (int k = khi; k >= klo; --k) {
      const int r = k - klo;
      // candidates c_i = fl(fl(ph_k[i]+trans[i,ptr]) + e), i = 2l, 2l+1
      const float2 P  = *(const float2*)(Prow + r * T_ + 2 * lane);
      const float2 tr = *(const float2*)(transT + ptr * TS_ + 2 * lane);
      float cx = (P.x + tr.x) + e;
      float cy = (P.y + tr.y) + e;
      unsigned long long q0 = __ballot(cx == tg);
      unsigned long long q1 = __ballot(cy == tg);
      int a0 = q0 ? 2 * (__ffsll(q0) - 1)     : (1 << 30);
      int a1 = q1 ? 2 * (__ffsll(q1) - 1) + 1 : (1 << 30);
      ptr = min(a0, a1);
      if (lane == 0) out[b * S_ + k] = ptr;
      // next step (k-1) targets ph[k][ptr] and feats[k][ptr]
      tg = readlane_f((ptr & 1) ? P.y : P.x, ptr >> 1);
      e  = Frow[r * T_ + ptr];           // broadcast read, used next step
    }
    if (w > 0) write_lds(cur ^ 1);
    cur ^= 1;
    khi = klo - 1;
  }
}

extern "C" void kernel_launch(void* const* d_in, const int* in_sizes, int n_in,
                              void* d_out, int out_size, void* d_ws, size_t ws_size,
                              hipStream_t stream) {
  const float* feats = (const float*)d_in[0];   // (B,S,T) fp32
  const void*  mask  = d_in[1];                 // (B,S) bool-ish
  const float* trans = (const float*)d_in[2];   // (T,T) fp32
  float* ph = (float*)d_ws;                     // (B,S,T) fp32 = 64 MB
  int*   out = (int*)d_out;                     // (B,S) int32

  viterbi_forward<<<dim3(B_), dim3(1024), 0, stream>>>(feats, trans, ph);
  viterbi_trace  <<<dim3(B_), dim3(64), 0, stream>>>(feats, mask, trans, ph, out);
}

// Round 9
// 421.416 us; speedup vs baseline: 1.0443x; 1.0443x over previous
//
#include <hip/hip_runtime.h>
#include <cstdint>
#include <cstddef>

constexpr int T_ = 128;
constexpr int S_ = 512;
constexpr int B_ = 256;
constexpr int START_ = T_ - 3;  // 125
constexpr int STOP_  = T_ - 2;  // 126

typedef float f32x2 __attribute__((ext_vector_type(2)));

// Barrier that only drains LDS (lgkmcnt), NOT vmcnt: global ph-stores and
// e-prefetch loads legally stay in flight across it (thread-private data).
// Every wave drains its own LDS reads+writes before arriving, so the
// read-then-rewrite ping-pong across one barrier is race-free (R4-R8 proven).
__device__ __forceinline__ void lds_barrier() {
  asm volatile("s_waitcnt lgkmcnt(0)\n\ts_barrier" ::: "memory");
}

// readlane: wave-uniform lane index (SGPR) -> ~VALU-speed broadcast.
__device__ __forceinline__ float readlane_f(float v, int sl) {
  return __int_as_float(__builtin_amdgcn_readlane(__float_as_int(v), sl));
}

__device__ __forceinline__ f32x2 max2(f32x2 a, f32x2 b) {
  return __builtin_elementwise_max(a, b);
}

// packed DPP max stage: 2x mov_dpp + 1x v_pk_max_f32
template <int CTRL>
__device__ __forceinline__ f32x2 dpp_max2(f32x2 m) {
  int lo = __builtin_amdgcn_mov_dpp(__float_as_int(m.x), CTRL, 0xF, 0xF, true);
  int hi = __builtin_amdgcn_mov_dpp(__float_as_int(m.y), CTRL, 0xF, 0xF, true);
  f32x2 o; o.x = __int_as_float(lo); o.y = __int_as_float(hi);
  return max2(m, o);
}
// reduce over the 16 ig-lanes (lane bits [0,4)) in pure row-DPP (R7-proven
// stages): quad xor1 (0xB1), quad xor2 (0x4E), row_half_mirror (0x141),
// row_mirror (0x140).
__device__ __forceinline__ f32x2 ig16_rmax2(f32x2 m) {
  m = dpp_max2<0xB1>(m);
  m = dpp_max2<0x4E>(m);
  m = dpp_max2<0x141>(m);
  m = dpp_max2<0x140>(m);
  return m;
}

// ---------------------------------------------------------------------------
// Forward: value-only Viterbi recursion, stores part_hist as (B,S,T) fp32.
// 1024 threads (4 waves/SIMD). Thread (ig,jg): i in [8ig,8ig+8) x j={2jg,2jg+1}.
// R9 changes vs R8 (which showed VGPR_Count=28 => tile in AGPRs, ~890 cyc
// VALU issue/SIMD/step vs ~480 expected):
//  - packed-fp32 core: candidates paired over i (pairs come straight from
//    the b128 part load + packed tcp preload), 4 pk_add + 3 pk_max + lo/hi
//    fold per j; both j-partials packed into one f32x2 for the DPP reduce.
//  - static buffer parity (tb-loop; parity = u&1 at compile time).
//  - clamp-free e-prefetch: 63 full 8-step groups + explicit 7-step tail.
// Bit-exact: max exactly associative, fl monotone =>
//   max_i fl(fl(p+tr)+e) == fl(max_i fl(p+tr) + e).
// ---------------------------------------------------------------------------
__global__ __launch_bounds__(1024, 4) void viterbi_forward(
    const float* __restrict__ feats,   // (B,S,T)
    const float* __restrict__ trans,   // (T,T)
    float* __restrict__ ph)            // (B,S,T) workspace
{
  const int b    = blockIdx.x;
  const int tid  = threadIdx.x;
  const int lane = tid & 63;
  const int ig   = lane & 15;          // i-chunk: i in [8ig, 8ig+8)
  const int jg   = tid >> 4;           // 0..63
  const int j0   = jg * 2;

  // padded part: value i at float offset i + 4*(i>>3); granules 3a,3a+1
  __shared__ alignas(16) float part[2][192];

  // packed trans tile: tcp[c][a] = {trans[8ig+2a][j0+c], trans[8ig+2a+1][j0+c]}
  f32x2 tcp[2][4];
  #pragma unroll
  for (int a = 0; a < 4; ++a) {
    f32x2 r0 = *(const f32x2*)&trans[(8 * ig + 2 * a)     * T_ + j0];
    f32x2 r1 = *(const f32x2*)&trans[(8 * ig + 2 * a + 1) * T_ + j0];
    tcp[0][a].x = r0.x; tcp[0][a].y = r1.x;
    tcp[1][a].x = r0.y; tcp[1][a].y = r1.y;
  }

  const float* fb  = feats + (size_t)b * S_ * T_;
  float*       phb = ph    + (size_t)b * S_ * T_;
  const int woff   = j0 + 4 * (j0 >> 3);

  // t = 0: part0 = emit[0] + trans[START,:]
  f32x2 e0 = *(const f32x2*)&fb[j0];
  f32x2 ts = *(const f32x2*)&trans[START_ * T_ + j0];
  f32x2 p0 = e0 + ts;
  if (ig == 0) {
    *(f32x2*)&part[0][woff] = p0;
    *(f32x2*)&phb[j0] = p0;
  }
  __syncthreads();

  auto stepf = [&](const float* rbuf, float* wbuf, float* phrow, f32x2 e2) {
    const float4* p4 = (const float4*)rbuf;
    float4 pa = p4[3 * ig];
    float4 pb = p4[3 * ig + 1];
    f32x2 pv0 = {pa.x, pa.y}, pv1 = {pa.z, pa.w};
    f32x2 pv2 = {pb.x, pb.y}, pv3 = {pb.z, pb.w};
    f32x2 m01;
    {
      f32x2 mm = max2(max2(pv0 + tcp[0][0], pv1 + tcp[0][1]),
                      max2(pv2 + tcp[0][2], pv3 + tcp[0][3]));
      m01.x = fmaxf(mm.x, mm.y);
    }
    {
      f32x2 mm = max2(max2(pv0 + tcp[1][0], pv1 + tcp[1][1]),
                      max2(pv2 + tcp[1][2], pv3 + tcp[1][3]));
      m01.y = fmaxf(mm.x, mm.y);
    }
    f32x2 np = ig16_rmax2(m01) + e2;
    if (ig == 0) *(f32x2*)&part[0][(wbuf - part[0]) + woff] = np;
    lds_barrier();
    if (ig == 0) *(f32x2*)&phrow[j0] = np;   // off critical path
  };

  // e-prefetch: 8 rows in flight, clamp-free for the 63 full groups
  f32x2 EA[4], EB[4];
  const float* pf = fb + j0 + T_;            // next row to fetch (t=1)
  #pragma unroll
  for (int u = 0; u < 4; ++u) { EA[u] = *(const f32x2*)pf; pf += T_; }

  float* phrow = phb + T_;                   // ph row t=1
  for (int tb = 0; tb < 63; ++tb) {          // t = 8tb+1 .. 8tb+8
    #pragma unroll
    for (int u = 0; u < 4; ++u) { EB[u] = *(const f32x2*)pf; pf += T_; }
    #pragma unroll
    for (int u = 0; u < 4; ++u) {            // parity static: read u&1
      stepf(part[u & 1], part[(u + 1) & 1], phrow, EA[u]); phrow += T_;
    }
    #pragma unroll
    for (int u = 0; u < 4; ++u) { EA[u] = *(const f32x2*)pf; pf += T_; }
    #pragma unroll
    for (int u = 0; u < 4; ++u) {
      stepf(part[u & 1], part[(u + 1) & 1], phrow, EB[u]); phrow += T_;
    }
  }
  // tail: t = 505..511 (EA holds rows 505..508; fetch 509..511)
  f32x2 ET[3];
  #pragma unroll
  for (int u = 0; u < 3; ++u) { ET[u] = *(const f32x2*)pf; pf += T_; }
  #pragma unroll
  for (int u = 0; u < 4; ++u) {
    stepf(part[u & 1], part[(u + 1) & 1], phrow, EA[u]); phrow += T_;
  }
  #pragma unroll
  for (int u = 0; u < 3; ++u) {
    stepf(part[u & 1], part[(u + 1) & 1], phrow, ET[u]); phrow += T_;
  }
}

// ---------------------------------------------------------------------------
// Trace: one wave per b, grid 256 — R7's proven structure (equality-ballot
// on-path bp recompute, named A/B register chunks 8 steps deep), adapted to
// the (B,S,T) ph layout (per-b rows contiguous). Bit-exact first-occurrence
// argmax vs reference.
// ---------------------------------------------------------------------------
constexpr int CH_ = 8;   // chunk size (steps per buffer)
constexpr int TS_ = 130; // transT row stride (even: float2-aligned, 2-way ok)

__global__ __launch_bounds__(64, 1) void viterbi_trace(
    const float* __restrict__ feats,   // (B,S,T)
    const void*  __restrict__ mask,    // (B,S) dtype detected at runtime
    const float* __restrict__ trans,   // (T,T)
    const float* __restrict__ ph,      // (B,S,T)
    int* __restrict__ out)             // (B,S) int32
{
  const int b    = blockIdx.x;
  const int lane = threadIdx.x;

  __shared__ alignas(16) float transT[T_ * TS_];  // transT[j*TS+i]=trans[i][j]
  #pragma unroll 4
  for (int g = lane; g < T_ * T_; g += 64) {
    int i = g >> 7, jj = g & (T_ - 1);
    transT[jj * TS_ + i] = trans[g];
  }
  __syncthreads();

  // ---- sequence length (mask dtype: uint8 / float32 / int32) ----
  int len = 0;
  {
    const int w0m = *(const int*)mask;  // element (0,0) is always true
    if (w0m == 0x01010101) {
      const unsigned char* m = (const unsigned char*)mask + (size_t)b * S_;
      for (int s = lane; s < S_; s += 64) len += (m[s] != 0);
    } else if (w0m == 0x3F800000) {
      const float* m = (const float*)mask + (size_t)b * S_;
      for (int s = lane; s < S_; s += 64) len += (m[s] != 0.0f);
    } else {
      const int* m = (const int*)mask + (size_t)b * S_;
      for (int s = lane; s < S_; s += 64) len += (m[s] != 0);
    }
    #pragma unroll
    for (int o = 32; o > 0; o >>= 1) len += __shfl_xor(len, o);
  }
  const int lp = len - 1;              // last valid position (>= 255)

  const float* phb = ph    + (size_t)b * S_ * T_;
  const float* fb  = feats + (size_t)b * S_ * T_;

  // ---- final pointer: first argmax_i(ph_lp[i] + trans[i][STOP]) ----
  const float2 L = *(const float2*)(phb + (size_t)lp * T_ + 2 * lane);
  float v0 = L.x + transT[STOP_ * TS_ + 2 * lane];
  float v1 = L.y + transT[STOP_ * TS_ + 2 * lane + 1];
  float mx = fmaxf(v0, v1);
  #pragma unroll
  for (int o = 32; o > 0; o >>= 1) mx = fmaxf(mx, __shfl_xor(mx, o));
  {
    unsigned long long g0 = __ballot(v0 == mx);
    unsigned long long g1 = __ballot(v1 == mx);
    int p0 = g0 ? 2 * (__ffsll(g0) - 1)     : (1 << 30);
    int p1 = g1 ? 2 * (__ffsll(g1) - 1) + 1 : (1 << 30);
    int pointer = min(p0, p1);

    // ---- masked tail: out[k]=0 for lp<k<S-1; out[S-1]=out[lp]=pointer ----
    for (int k = lp + 1 + lane; k <= S_ - 2; k += 64) out[b * S_ + k] = 0;
    if (lane == 0) {
      out[b * S_ + (S_ - 1)] = pointer;
      if (lp < S_ - 1) out[b * S_ + lp] = pointer;
    }

    // ---- chase k = lp-1 .. 0 ----
    int   ptr = pointer;
    float tg  = readlane_f((ptr & 1) ? L.y : L.x, ptr >> 1);  // ph[lp][ptr]
    const float2 FL = *(const float2*)(fb + (size_t)lp * T_ + 2 * lane);
    float e = readlane_f((ptr & 1) ? FL.y : FL.x, ptr >> 1);  // feats[lp][ptr]

    float2 PA[CH_], FA[CH_], PB[CH_], FB[CH_];

    auto issue = [&](float2 (&P)[CH_], float2 (&F)[CH_], int k0) {
      #pragma unroll
      for (int s = 0; s < CH_; ++s) {
        int k = k0 - s; if (k < 0) k = 0;     // clamped slots never used
        P[s] = *(const float2*)(phb + (size_t)k * T_ + 2 * lane);
        F[s] = *(const float2*)(fb  + (size_t)k * T_ + 2 * lane);
      }
    };
    auto process = [&](const float2 (&P)[CH_], const float2 (&F)[CH_], int k0) {
      #pragma unroll
      for (int s = 0; s < CH_; ++s) {
        const int k = k0 - s;
        if (k >= 0) {
          // candidates c_i = fl(fl(ph_k[i]+trans[i,ptr]) + e), i = 2l, 2l+1
          const float2 tr = *(const float2*)(transT + ptr * TS_ + 2 * lane);
          float cx = (P[s].x + tr.x) + e;
          float cy = (P[s].y + tr.y) + e;
          unsigned long long q0 = __ballot(cx == tg);
          unsigned long long q1 = __ballot(cy == tg);
          int a0 = q0 ? 2 * (__ffsll(q0) - 1)     : (1 << 30);
          int a1 = q1 ? 2 * (__ffsll(q1) - 1) + 1 : (1 << 30);
          ptr = min(a0, a1);
          if (lane == 0) out[b * S_ + k] = ptr;
          // next step (k-1) targets ph[k][ptr], feats[k][ptr]
          tg = readlane_f((ptr & 1) ? P[s].y : P[s].x, ptr >> 1);
          e  = readlane_f((ptr & 1) ? F[s].y : F[s].x, ptr >> 1);
        }
      }
    };

    issue(PA, FA, lp - 1);
    for (int k0 = lp - 1; k0 >= 0; k0 -= 2 * CH_) {
      issue(PB, FB, k0 - CH_);
      process(PA, FA, k0);
      issue(PA, FA, k0 - 2 * CH_);
      process(PB, FB, k0 - CH_);
    }
  }
}

extern "C" void kernel_launch(void* const* d_in, const int* in_sizes, int n_in,
                              void* d_out, int out_size, void* d_ws, size_t ws_size,
                              hipStream_t stream) {
  const float* feats = (const float*)d_in[0];   // (B,S,T) fp32
  const void*  mask  = d_in[1];                 // (B,S) bool-ish
  const float* trans = (const float*)d_in[2];   // (T,T) fp32
  float* ph = (float*)d_ws;                     // (B,S,T) fp32 = 64 MB
  int*   out = (int*)d_out;                     // (B,S) int32

  viterbi_forward<<<dim3(B_), dim3(1024), 0, stream>>>(feats, trans, ph);
  viterbi_trace  <<<dim3(B_), dim3(64), 0, stream>>>(feats, mask, trans, ph, out);
}